// Round 3
// baseline (324.847 us; speedup 1.0000x reference)
//
#include <hip/hip_runtime.h>
#include <hip/hip_bf16.h>
#include <stdint.h>

// Problem constants (match setup_inputs)
#define B_  4
#define S_  2048
#define E_  1024
#define H_  16
#define HD_ 64
#define JD_ 25            // observation_dim + action_dim + 2
#define M_  (B_ * S_)     // 8192 rows for the projections
#define SE_ ((size_t)B_ * S_ * E_)          // 8,388,608
#define EE_ ((size_t)E_ * E_)               // 1,048,576

// Q pre-scale: (1/sqrt(64)) * log2(e) -> scores in log2 domain, exp2 softmax
#define QSCALE 0.18033688011112042f

// workspace layout (ushort units)
#define OFF_HSB  ((size_t)0)
#define OFF_W(i) (SE_ + (size_t)(i) * EE_)
#define OFF_B(i) (SE_ + 4 * EE_ + (size_t)(i) * E_)
#define OFF_Q    (SE_ + 4 * EE_ + 4 * (size_t)E_)
#define OFF_K    (OFF_Q + SE_)
#define OFF_V    (OFF_K + SE_)   // holds V^T: [feature][b*S+s], row stride M_
#define OFF_O    (OFF_V + SE_)

typedef __attribute__((ext_vector_type(8))) short bf16x8;  // 8 bf16 = 4 VGPRs
typedef __attribute__((ext_vector_type(4))) float f32x4;

__device__ __forceinline__ float b2f(ushort u) {
  union { uint32_t i; float f; } x; x.i = ((uint32_t)u) << 16; return x.f;
}
__device__ __forceinline__ ushort f2b(float f) {
  union { float f; uint32_t i; } x; x.f = f;
  uint32_t i = x.i;
  uint32_t r = (i + 0x7FFFu + ((i >> 16) & 1u)) >> 16;
  return (ushort)r;
}

// Runtime dtype detection on hidden_states (bf16-served vs fp32-served).
__device__ bool detect_bf16(const ushort* det) {
  int sane = 0;
#pragma unroll
  for (int i = 0; i < 32; ++i) {
    ushort u = det[2 * i];
    int e = (u >> 7) & 0xFF;
    sane += (e >= 90 && e <= 150) ? 1 : 0;
  }
  return sane >= 24;
}

__device__ __forceinline__ void async16(const void* g, void* l) {
  __builtin_amdgcn_global_load_lds(
      (const __attribute__((address_space(1))) uint32_t*)g,
      (__attribute__((address_space(3))) uint32_t*)l, 16, 0, 0);
}

// ============================================================================
// Normalize all float inputs to bf16 copies in ws.
// ============================================================================
__global__ __launch_bounds__(256)
void convert_kernel(const void* hs, const void* wq, const void* wk,
                    const void* wv, const void* wp,
                    const void* bq, const void* bk, const void* bv, const void* bp,
                    ushort* ws)
{
  __shared__ int dflag;
  if (threadIdx.x == 0) dflag = detect_bf16((const ushort*)hs) ? 1 : 0;
  __syncthreads();
  const bool isb = (dflag != 0);

  const void* src; ushort* dst; size_t n;
  switch (blockIdx.y) {
    case 0: src = hs; dst = ws + OFF_HSB;  n = SE_;        break;
    case 1: src = wq; dst = ws + OFF_W(0); n = EE_;        break;
    case 2: src = wk; dst = ws + OFF_W(1); n = EE_;        break;
    case 3: src = wv; dst = ws + OFF_W(2); n = EE_;        break;
    case 4: src = wp; dst = ws + OFF_W(3); n = EE_;        break;
    case 5: src = bq; dst = ws + OFF_B(0); n = (size_t)E_; break;
    case 6: src = bk; dst = ws + OFF_B(1); n = (size_t)E_; break;
    case 7: src = bv; dst = ws + OFF_B(2); n = (size_t)E_; break;
    default: src = bp; dst = ws + OFF_B(3); n = (size_t)E_; break;
  }
  size_t nv = n >> 2;
  for (size_t i = blockIdx.x * (size_t)blockDim.x + threadIdx.x; i < nv;
       i += (size_t)gridDim.x * blockDim.x) {
    ushort4 o;
    if (isb) {
      o = ((const ushort4*)src)[i];
    } else {
      float4 f = ((const float4*)src)[i];
      o.x = f2b(f.x); o.y = f2b(f.y); o.z = f2b(f.z); o.w = f2b(f.w);
    }
    ((ushort4*)dst)[i] = o;
  }
}

// ============================================================================
// NT GEMM: C[M,N] = (A[M,K] * W[N,K]^T + bias) * scale  (bf16 in, fp32 acc)
// 128x128 tile, BK=64, 256 threads. grid.z selects (W,bias,C).
// LDS tiles XOR-swizzled (chunk c of row r stored at c^(r&7); pre-swizzled
// global source) -> conflict-free ds_read_b128 at 128B row stride.
// ============================================================================
__global__ __launch_bounds__(256, 4)
void gemm_nt_bias(const ushort* __restrict__ X,
                  const ushort* __restrict__ W0, const ushort* __restrict__ b0, void* __restrict__ C0,
                  const ushort* __restrict__ W1, const ushort* __restrict__ b1, void* __restrict__ C1,
                  const ushort* __restrict__ W2, const ushort* __restrict__ b2, void* __restrict__ C2,
                  int M, int N, int Kd, const ushort* det, int detect_out, int tz, int scalez)
{
  const ushort* W  = (blockIdx.z == 0) ? W0 : (blockIdx.z == 1) ? W1 : W2;
  const ushort* bi = (blockIdx.z == 0) ? b0 : (blockIdx.z == 1) ? b1 : b2;
  void*         C  = (blockIdx.z == 0) ? C0 : (blockIdx.z == 1) ? C1 : C2;
  const bool tstore = ((int)blockIdx.z == tz);
  const float scl  = ((int)blockIdx.z == scalez) ? QSCALE : 1.0f;

  __shared__ ushort lA[128 * 64];   // 16KB, swizzled
  __shared__ ushort lB[128 * 64];   // 16KB, swizzled
  __shared__ int dflag;
  if (threadIdx.x == 0) dflag = (detect_out && !detect_bf16(det)) ? 1 : 0;
  __syncthreads();
  const bool f32out = (dflag != 0);

  const int tid  = threadIdx.x;
  const int lane = tid & 63;
  const int wv   = tid >> 6;
  const int m0   = blockIdx.x * 128;
  const int n0   = blockIdx.y * 128;
  const int wr   = (wv >> 1) * 64;
  const int wc   = (wv & 1) * 64;
  const int ml   = lane & 15;
  const int qd   = lane >> 4;
  const int sx   = ml & 7;          // XOR swizzle key for fragment reads

  f32x4 acc[4][4];
#pragma unroll
  for (int i = 0; i < 4; ++i)
#pragma unroll
    for (int j = 0; j < 4; ++j)
      acc[i][j] = (f32x4){0.f, 0.f, 0.f, 0.f};

  // staging: tile = 128 rows x 64 cols (8 chunks of 16B per row).
  // stored chunk s (= i*256 + wv*64 + lane) holds data chunk (s&7)^(row&7)
  // of row s>>3 -> lane loads permuted global address, LDS dest stays linear.
  const int r0s = (wv * 64 + lane) >> 3;          // 0..31, +32 per issue
  const int c0s = (lane & 7) ^ (r0s & 7);
  const ushort* gA = X + (size_t)(m0 + r0s) * Kd + c0s * 8;
  const ushort* gW = W + (size_t)(n0 + r0s) * Kd + c0s * 8;
  char* lAb = (char*)lA + (size_t)wv * 1024;
  char* lBb = (char*)lB + (size_t)wv * 1024;

  for (int k0 = 0; k0 < Kd; k0 += 64) {
#pragma unroll
    for (int i = 0; i < 4; ++i) {
      async16(gA + k0 + (size_t)(32 * i) * Kd, lAb + i * 4096);
      async16(gW + k0 + (size_t)(32 * i) * Kd, lBb + i * 4096);
    }
    __syncthreads();

#pragma unroll
    for (int kk = 0; kk < 2; ++kk) {
      bf16x8 af[4], bfr[4];
#pragma unroll
      for (int i = 0; i < 4; ++i)
        af[i] = *(const bf16x8*)&lA[(wr + i * 16 + ml) * 64 + (((kk * 4 + qd) ^ sx) * 8)];
#pragma unroll
      for (int j = 0; j < 4; ++j)
        bfr[j] = *(const bf16x8*)&lB[(wc + j * 16 + ml) * 64 + (((kk * 4 + qd) ^ sx) * 8)];
#pragma unroll
      for (int i = 0; i < 4; ++i)
#pragma unroll
        for (int j = 0; j < 4; ++j)
          acc[i][j] = __builtin_amdgcn_mfma_f32_16x16x32_bf16(af[i], bfr[j], acc[i][j], 0, 0, 0);
    }
    __syncthreads();
  }

  // epilogue: C/D layout col=lane&15, row=quad*4+reg
#pragma unroll
  for (int j = 0; j < 4; ++j) {
    int col = n0 + wc + j * 16 + ml;
    float bv = b2f(bi[col]);
#pragma unroll
    for (int i = 0; i < 4; ++i) {
      int row0 = m0 + wr + i * 16 + qd * 4;
      if (tstore) {
        ushort4 pk;
        pk.x = f2b((acc[i][j][0] + bv) * scl);
        pk.y = f2b((acc[i][j][1] + bv) * scl);
        pk.z = f2b((acc[i][j][2] + bv) * scl);
        pk.w = f2b((acc[i][j][3] + bv) * scl);
        *(ushort4*)((ushort*)C + (size_t)col * M + row0) = pk;
      } else if (f32out) {
        float* cp = (float*)C + (size_t)row0 * N + col;
#pragma unroll
        for (int r = 0; r < 4; ++r)
          cp[(size_t)r * N] = (acc[i][j][r] + bv) * scl;
      } else {
        ushort* cp = (ushort*)C + (size_t)row0 * N + col;
#pragma unroll
        for (int r = 0; r < 4; ++r)
          cp[(size_t)r * N] = f2b((acc[i][j][r] + bv) * scl);
      }
    }
  }
}

// ============================================================================
// Flash attention, periodic causal mask. Round-3 changes:
//  - l-sum via ones-B MFMA: lC = mfma(ones_frag, P^T_frag, lC). Every lane's
//    reg = sum_k P[k][q=ml] accumulated across kts -> no per-tile add tree,
//    no epilogue shuffles.
//  - mask: post-hoc cndmask (bad-column bits + causal bits merged into one
//    64-bit mask) before exp2; zero C-init -> no long-lived sbias regs.
//  - V single-buffered (LDS 40KB -> 32KB = 5 blocks/CU): V[kt] issued at the
//    top of the iter, mid-iter __syncthreads between softmax(T0) and PV(T0).
//  - s_setprio(1) around MFMA clusters.
// K double-buffered, global_load_lds(16B), XOR-swizzled tiles. 1024 blocks,
// XCD-swizzled.
// ============================================================================
__device__ __forceinline__ void qksm(const ushort* bK, const bf16x8 qf0, const bf16x8 qf1,
                                     int qabs, int kt, uint64_t good, bool diag,
                                     ushort* pw, int ml, int qd, int sx,
                                     bf16x8& pa0, bf16x8& pa1)
{
  const f32x4 zf = {0.f, 0.f, 0.f, 0.f};
  f32x4 sv[4];
  __builtin_amdgcn_s_setprio(1);
#pragma unroll
  for (int kb = 0; kb < 4; ++kb) {
    f32x4 s = zf;
    const ushort* krow = &bK[(kb * 16 + ml) * 64];
    s = __builtin_amdgcn_mfma_f32_16x16x32_bf16(*(const bf16x8*)&krow[(qd ^ sx) * 8],       qf0, s, 0, 0, 0);
    s = __builtin_amdgcn_mfma_f32_16x16x32_bf16(*(const bf16x8*)&krow[((qd + 4) ^ sx) * 8], qf1, s, 0, 0, 0);
    sv[kb] = s;
  }
  __builtin_amdgcn_s_setprio(0);

  // merged mask (bad columns; + causal on diagonal tile) -> -1e30 -> exp2 -> 0
  uint64_t mm = good;
  if (diag) {
    const int qrel = qabs - kt * 64;
    uint64_t keep = (qrel >= 63) ? ~0ull : ((1ull << (qrel + 1)) - 1ull);
    mm &= keep;
  }
  const uint64_t gq = mm >> (qd * 4);
  const uint32_t g_lo = (uint32_t)gq, g_hi = (uint32_t)(gq >> 32);
#pragma unroll
  for (int kb = 0; kb < 4; ++kb) {
    const uint32_t kh = (kb & 1) ? ((kb & 2) ? (g_hi >> 16) : (g_lo >> 16))
                                 : ((kb & 2) ? g_hi : g_lo);
#pragma unroll
    for (int r = 0; r < 4; ++r) {
      float x = ((kh >> r) & 1u) ? sv[kb][r] : -1.0e30f;
      sv[kb][r] = __builtin_exp2f(x);
    }
  }

  // P^T -> swizzled per-wave LDS [q][key], read back as B-frags (same wave,
  // in-order DS: no barrier needed)
  const int sub = (qd & 1) * 4;
#pragma unroll
  for (int kb = 0; kb < 4; ++kb) {
    uint32_t plo, phi;
    asm("v_cvt_pk_bf16_f32 %0, %1, %2" : "=v"(plo) : "v"(sv[kb][0]), "v"(sv[kb][1]));
    asm("v_cvt_pk_bf16_f32 %0, %1, %2" : "=v"(phi) : "v"(sv[kb][2]), "v"(sv[kb][3]));
    const int s_ = (kb * 2 + (qd >> 1)) ^ sx;
    uint2 pk; pk.x = plo; pk.y = phi;
    *(uint2*)&pw[ml * 64 + s_ * 8 + sub] = pk;
  }
  pa0 = *(const bf16x8*)&pw[ml * 64 + ((qd ^ sx)) * 8];
  pa1 = *(const bf16x8*)&pw[ml * 64 + (((qd + 4) ^ sx)) * 8];
}

__device__ __forceinline__ void pvstep(const ushort* bV, bf16x8 pa0, bf16x8 pa1,
                                       bf16x8 ones, int ml, int qd, int sx,
                                       f32x4* oaccT, f32x4& lCT)
{
  __builtin_amdgcn_s_setprio(1);
#pragma unroll
  for (int nb = 0; nb < 4; ++nb) {
    const ushort* vrow = &bV[(nb * 16 + ml) * 64];
    oaccT[nb] = __builtin_amdgcn_mfma_f32_16x16x32_bf16(*(const bf16x8*)&vrow[(qd ^ sx) * 8],       pa0, oaccT[nb], 0, 0, 0);
    oaccT[nb] = __builtin_amdgcn_mfma_f32_16x16x32_bf16(*(const bf16x8*)&vrow[((qd + 4) ^ sx) * 8], pa1, oaccT[nb], 0, 0, 0);
  }
  // l-sum: ones(A) x P^T(B): every reg = sum_k P[k][q=ml]
  lCT = __builtin_amdgcn_mfma_f32_16x16x32_bf16(ones, pa0, lCT, 0, 0, 0);
  lCT = __builtin_amdgcn_mfma_f32_16x16x32_bf16(ones, pa1, lCT, 0, 0, 0);
  __builtin_amdgcn_s_setprio(0);
}

__global__ __launch_bounds__(256, 5)
void attn_kernel(const ushort* __restrict__ Qg, const ushort* __restrict__ Kg,
                 const ushort* __restrict__ Vt, ushort* __restrict__ Og)
{
  __shared__ ushort lK[2][64 * 64];   // [key][d] swizzled, 8KB each
  __shared__ ushort lV[64 * 64];      // [d][key] swizzled, single buffer
  __shared__ ushort lP[4][16 * 64];   // per-wave P^T [q][key] swizzled
  // total 32KB -> 5 blocks/CU

  // XCD-aware decode: xcd = lin&7; all 16 p-blocks of a bh on one XCD
  const int lin = blockIdx.x;
  const int bh  = (lin & 7) * 8 + (lin >> 7);       // 0..63
  const int p   = (lin >> 3) & 15;                  // 0..15
  const int b = bh >> 4, h = bh & 15;
  const size_t base = (size_t)b * S_ * E_ + (size_t)h * HD_;   // Q,K,O
  const ushort* vtb = Vt + (size_t)(h * HD_) * M_ + (size_t)b * S_;

  const int tid  = threadIdx.x;
  const int lane = tid & 63;
  const int wv   = tid >> 6;
  const int ml   = lane & 15;
  const int qd   = lane >> 4;
  const int sx   = ml & 7;            // XOR swizzle key for this lane's reads

  const int qthi = 31 - p, qtlo = p;
  const int q0t[2] = { qthi * 64 + wv * 16, qtlo * 64 + wv * 16 };
  const int ktmax = qthi;

  // Q B-frags: lane n=ml -> query q0t[T]+ml; k = half*32 + qd*8 + j
  bf16x8 qf[2][2];
#pragma unroll
  for (int T = 0; T < 2; ++T) {
    const ushort* qp = Qg + base + (size_t)(q0t[T] + ml) * E_ + qd * 8;
    qf[T][0] = *(const bf16x8*)qp;
    qf[T][1] = *(const bf16x8*)(qp + 32);
  }

  f32x4 oacc[2][4];
  f32x4 lC2[2];
#pragma unroll
  for (int T = 0; T < 2; ++T) {
#pragma unroll
    for (int nb = 0; nb < 4; ++nb) oacc[T][nb] = (f32x4){0.f, 0.f, 0.f, 0.f};
    lC2[T] = (f32x4){0.f, 0.f, 0.f, 0.f};
  }

  bf16x8 ones;
#pragma unroll
  for (int j = 0; j < 8; ++j) ones[j] = (short)0x3F80;   // bf16 1.0

  // staging: lane covers 16B chunk g; stored chunk s holds data chunk
  // s^(row&7) -> lane loads permuted global.
  const int g0 = (wv * 2) * 64 + lane;       // round 0 chunk id
  const int g1 = g0 + 64;                    // round 1
  const int r0 = g0 >> 3, c0 = ((g0 & 7) ^ (r0 & 7)) * 8;
  const int r1 = g1 >> 3, c1 = ((g1 & 7) ^ (r1 & 7)) * 8;
  const ushort* kS0 = Kg + base + (size_t)r0 * E_ + c0;
  const ushort* kS1 = Kg + base + (size_t)r1 * E_ + c1;
  const ushort* vS0 = vtb + (size_t)r0 * M_ + c0;
  const ushort* vS1 = vtb + (size_t)r1 * M_ + c1;
  const int d0 = (wv * 2) * 512, d1 = d0 + 512;   // ushort offsets, wave-uniform

#define ISSUE_K(bi_, t_) { size_t ko = (size_t)(t_) * 64 * E_; \
    async16(kS0 + ko, &lK[bi_][d0]); async16(kS1 + ko, &lK[bi_][d1]); }
#define ISSUE_V(t_) { int vo = (t_) * 64; \
    async16(vS0 + vo, &lV[d0]); async16(vS1 + vo, &lV[d1]); }

  ISSUE_K(0, 0);

  int rem = 0;                         // (kt*64) % JD_, incremental (+14 mod 25)
  for (int kt = 0; kt <= ktmax; ++kt) {
    __syncthreads();                   // K[kt] staged; V buffer free
    if (kt < ktmax) ISSUE_K((kt + 1) & 1, kt + 1);
    ISSUE_V(kt);
    const ushort* bK = lK[kt & 1];

    // bad-key bitmask for this tile: keys c, c+25, c+50 (c = JD_-1-rem)
    const int c = 24 - rem;
    rem += 14; if (rem >= 25) rem -= 25;
    const uint64_t good = ~(0x0004000002000001ull << c);

    // ---- T=0 (hi tile): QK + softmax + P staging ----
    bf16x8 pa0h, pa1h;
    qksm(bK, qf[0][0], qf[0][1], q0t[0] + ml, kt, good, kt == qthi,
         lP[wv], ml, qd, sx, pa0h, pa1h);

    __syncthreads();                   // V[kt] staged (drains vmcnt)

    // ---- PV for T=0 ----
    pvstep(lV, pa0h, pa1h, ones, ml, qd, sx, oacc[0], lC2[0]);

    // ---- T=1 (lo tile), while active ----
    if (kt <= qtlo) {
      bf16x8 pa0l, pa1l;
      qksm(bK, qf[1][0], qf[1][1], q0t[1] + ml, kt, good, kt == qtlo,
           lP[wv], ml, qd, sx, pa0l, pa1l);
      pvstep(lV, pa0l, pa1l, ones, ml, qd, sx, oacc[1], lC2[1]);
    }
  }
#undef ISSUE_K
#undef ISSUE_V

  // epilogue: lane owns query q0t[T]+ml; l = lC2[T][0] (all regs equal).
  // d = nb*16 + qd*4 + r (4 contiguous)
#pragma unroll
  for (int T = 0; T < 2; ++T) {
    const float inv = 1.0f / lC2[T][0];
    const int q = q0t[T] + ml;
#pragma unroll
    for (int nb = 0; nb < 4; ++nb) {
      const float a0 = oacc[T][nb][0] * inv;
      const float a1 = oacc[T][nb][1] * inv;
      const float a2 = oacc[T][nb][2] * inv;
      const float a3 = oacc[T][nb][3] * inv;
      uint32_t olo, ohi;
      asm("v_cvt_pk_bf16_f32 %0, %1, %2" : "=v"(olo) : "v"(a0), "v"(a1));
      asm("v_cvt_pk_bf16_f32 %0, %1, %2" : "=v"(ohi) : "v"(a2), "v"(a3));
      uint2 o; o.x = olo; o.y = ohi;
      *(uint2*)&Og[base + (size_t)q * E_ + nb * 16 + qd * 4] = o;
    }
  }
}

// ============================================================================
extern "C" void kernel_launch(void* const* d_in, const int* in_sizes, int n_in,
                              void* d_out, int out_size, void* d_ws, size_t ws_size,
                              hipStream_t stream) {
  const void* hs = d_in[0];
  const void* Wq = d_in[1];
  const void* bq = d_in[2];
  const void* Wk = d_in[3];
  const void* bk = d_in[4];
  const void* Wv = d_in[5];
  const void* bv = d_in[6];
  const void* Wp = d_in[7];
  const void* bp = d_in[8];

  ushort* ws = (ushort*)d_ws;
  ushort* hsb = ws + OFF_HSB;
  ushort* Wqb = ws + OFF_W(0);
  ushort* Wkb = ws + OFF_W(1);
  ushort* Wvb = ws + OFF_W(2);
  ushort* Wpb = ws + OFF_W(3);
  ushort* bqb = ws + OFF_B(0);
  ushort* bkb = ws + OFF_B(1);
  ushort* bvb = ws + OFF_B(2);
  ushort* bpb = ws + OFF_B(3);
  ushort* Qw  = ws + OFF_Q;
  ushort* Kw  = ws + OFF_K;
  ushort* Vw  = ws + OFF_V;   // V^T [feature][b*S+s]
  ushort* Ow  = ws + OFF_O;
  const ushort* det = (const ushort*)hs;

  dim3 blk(256, 1, 1);
  hipLaunchKernelGGL(convert_kernel, dim3(512, 9, 1), blk, 0, stream,
                     hs, Wq, Wk, Wv, Wp, bq, bk, bv, bp, ws);
  // fused QKV projections; z==2 (V) transposed store; z==0 (Q) scaled QSCALE
  hipLaunchKernelGGL(gemm_nt_bias, dim3(M_ / 128, E_ / 128, 3), blk, 0, stream,
                     hsb, Wqb, bqb, (void*)Qw, Wkb, bkb, (void*)Kw,
                     Wvb, bvb, (void*)Vw, M_, E_, E_, det, 0, 2, 0);
  // attention: 1024 1D blocks, XCD-swizzled, 5 blocks/CU
  hipLaunchKernelGGL(attn_kernel, dim3(1024, 1, 1), blk, 0, stream,
                     Qw, Kw, Vw, Ow);
  // output projection: d_out dtype detected at runtime
  hipLaunchKernelGGL(gemm_nt_bias, dim3(M_ / 128, E_ / 128, 1), blk, 0, stream,
                     Ow, Wpb, bpb, d_out, Wpb, bpb, d_out, Wpb, bpb, d_out,
                     M_, E_, E_, det, 1, -1, -1);
}

// Round 4
// 269.249 us; speedup vs baseline: 1.2065x; 1.2065x over previous
//
#include <hip/hip_runtime.h>
#include <hip/hip_bf16.h>
#include <stdint.h>

// Problem constants (match setup_inputs)
#define B_  4
#define S_  2048
#define E_  1024
#define H_  16
#define HD_ 64
#define JD_ 25            // observation_dim + action_dim + 2
#define M_  (B_ * S_)     // 8192 rows for the projections
#define SE_ ((size_t)B_ * S_ * E_)          // 8,388,608
#define EE_ ((size_t)E_ * E_)               // 1,048,576

// Q pre-scale: (1/sqrt(64)) * log2(e) -> scores in log2 domain, exp2 softmax
#define QSCALE 0.18033688011112042f

// workspace layout (ushort units)
#define OFF_HSB  ((size_t)0)
#define OFF_W(i) (SE_ + (size_t)(i) * EE_)
#define OFF_B(i) (SE_ + 4 * EE_ + (size_t)(i) * E_)
#define OFF_Q    (SE_ + 4 * EE_ + 4 * (size_t)E_)
#define OFF_K    (OFF_Q + SE_)
#define OFF_V    (OFF_K + SE_)   // holds V^T: [feature][b*S+s], row stride M_
#define OFF_O    (OFF_V + SE_)

typedef __attribute__((ext_vector_type(8))) short bf16x8;  // 8 bf16 = 4 VGPRs
typedef __attribute__((ext_vector_type(4))) float f32x4;

__device__ __forceinline__ float b2f(ushort u) {
  union { uint32_t i; float f; } x; x.i = ((uint32_t)u) << 16; return x.f;
}
__device__ __forceinline__ ushort f2b(float f) {
  union { float f; uint32_t i; } x; x.f = f;
  uint32_t i = x.i;
  uint32_t r = (i + 0x7FFFu + ((i >> 16) & 1u)) >> 16;
  return (ushort)r;
}

// Runtime dtype detection on hidden_states (bf16-served vs fp32-served).
__device__ bool detect_bf16(const ushort* det) {
  int sane = 0;
#pragma unroll
  for (int i = 0; i < 32; ++i) {
    ushort u = det[2 * i];
    int e = (u >> 7) & 0xFF;
    sane += (e >= 90 && e <= 150) ? 1 : 0;
  }
  return sane >= 24;
}

__device__ __forceinline__ void async16(const void* g, void* l) {
  __builtin_amdgcn_global_load_lds(
      (const __attribute__((address_space(1))) uint32_t*)g,
      (__attribute__((address_space(3))) uint32_t*)l, 16, 0, 0);
}

// ============================================================================
// Normalize all float inputs to bf16 copies in ws.
// ============================================================================
__global__ __launch_bounds__(256)
void convert_kernel(const void* hs, const void* wq, const void* wk,
                    const void* wv, const void* wp,
                    const void* bq, const void* bk, const void* bv, const void* bp,
                    ushort* ws)
{
  __shared__ int dflag;
  if (threadIdx.x == 0) dflag = detect_bf16((const ushort*)hs) ? 1 : 0;
  __syncthreads();
  const bool isb = (dflag != 0);

  const void* src; ushort* dst; size_t n;
  switch (blockIdx.y) {
    case 0: src = hs; dst = ws + OFF_HSB;  n = SE_;        break;
    case 1: src = wq; dst = ws + OFF_W(0); n = EE_;        break;
    case 2: src = wk; dst = ws + OFF_W(1); n = EE_;        break;
    case 3: src = wv; dst = ws + OFF_W(2); n = EE_;        break;
    case 4: src = wp; dst = ws + OFF_W(3); n = EE_;        break;
    case 5: src = bq; dst = ws + OFF_B(0); n = (size_t)E_; break;
    case 6: src = bk; dst = ws + OFF_B(1); n = (size_t)E_; break;
    case 7: src = bv; dst = ws + OFF_B(2); n = (size_t)E_; break;
    default: src = bp; dst = ws + OFF_B(3); n = (size_t)E_; break;
  }
  size_t nv = n >> 2;
  for (size_t i = blockIdx.x * (size_t)blockDim.x + threadIdx.x; i < nv;
       i += (size_t)gridDim.x * blockDim.x) {
    ushort4 o;
    if (isb) {
      o = ((const ushort4*)src)[i];
    } else {
      float4 f = ((const float4*)src)[i];
      o.x = f2b(f.x); o.y = f2b(f.y); o.z = f2b(f.z); o.w = f2b(f.w);
    }
    ((ushort4*)dst)[i] = o;
  }
}

// ============================================================================
// NT GEMM: C[M,N] = (A[M,K] * W[N,K]^T + bias) * scale  (bf16 in, fp32 acc)
// 128x128 tile, BK=64, 256 threads. grid.z selects (W,bias,C).
// LDS tiles XOR-swizzled (chunk c of row r stored at c^(r&7); pre-swizzled
// global source) -> conflict-free ds_read_b128 at 128B row stride.
// ============================================================================
__global__ __launch_bounds__(256, 4)
void gemm_nt_bias(const ushort* __restrict__ X,
                  const ushort* __restrict__ W0, const ushort* __restrict__ b0, void* __restrict__ C0,
                  const ushort* __restrict__ W1, const ushort* __restrict__ b1, void* __restrict__ C1,
                  const ushort* __restrict__ W2, const ushort* __restrict__ b2, void* __restrict__ C2,
                  int M, int N, int Kd, const ushort* det, int detect_out, int tz, int scalez)
{
  const ushort* W  = (blockIdx.z == 0) ? W0 : (blockIdx.z == 1) ? W1 : W2;
  const ushort* bi = (blockIdx.z == 0) ? b0 : (blockIdx.z == 1) ? b1 : b2;
  void*         C  = (blockIdx.z == 0) ? C0 : (blockIdx.z == 1) ? C1 : C2;
  const bool tstore = ((int)blockIdx.z == tz);
  const float scl  = ((int)blockIdx.z == scalez) ? QSCALE : 1.0f;

  __shared__ ushort lA[128 * 64];   // 16KB, swizzled
  __shared__ ushort lB[128 * 64];   // 16KB, swizzled
  __shared__ int dflag;
  if (threadIdx.x == 0) dflag = (detect_out && !detect_bf16(det)) ? 1 : 0;
  __syncthreads();
  const bool f32out = (dflag != 0);

  const int tid  = threadIdx.x;
  const int lane = tid & 63;
  const int wv   = tid >> 6;
  const int m0   = blockIdx.x * 128;
  const int n0   = blockIdx.y * 128;
  const int wr   = (wv >> 1) * 64;
  const int wc   = (wv & 1) * 64;
  const int ml   = lane & 15;
  const int qd   = lane >> 4;
  const int sx   = ml & 7;          // XOR swizzle key for fragment reads

  f32x4 acc[4][4];
#pragma unroll
  for (int i = 0; i < 4; ++i)
#pragma unroll
    for (int j = 0; j < 4; ++j)
      acc[i][j] = (f32x4){0.f, 0.f, 0.f, 0.f};

  // staging: tile = 128 rows x 64 cols (8 chunks of 16B per row).
  // stored chunk s (= i*256 + wv*64 + lane) holds data chunk (s&7)^(row&7)
  // of row s>>3 -> lane loads permuted global address, LDS dest stays linear.
  const int r0s = (wv * 64 + lane) >> 3;          // 0..31, +32 per issue
  const int c0s = (lane & 7) ^ (r0s & 7);
  const ushort* gA = X + (size_t)(m0 + r0s) * Kd + c0s * 8;
  const ushort* gW = W + (size_t)(n0 + r0s) * Kd + c0s * 8;
  char* lAb = (char*)lA + (size_t)wv * 1024;
  char* lBb = (char*)lB + (size_t)wv * 1024;

  for (int k0 = 0; k0 < Kd; k0 += 64) {
#pragma unroll
    for (int i = 0; i < 4; ++i) {
      async16(gA + k0 + (size_t)(32 * i) * Kd, lAb + i * 4096);
      async16(gW + k0 + (size_t)(32 * i) * Kd, lBb + i * 4096);
    }
    __syncthreads();

#pragma unroll
    for (int kk = 0; kk < 2; ++kk) {
      bf16x8 af[4], bfr[4];
#pragma unroll
      for (int i = 0; i < 4; ++i)
        af[i] = *(const bf16x8*)&lA[(wr + i * 16 + ml) * 64 + (((kk * 4 + qd) ^ sx) * 8)];
#pragma unroll
      for (int j = 0; j < 4; ++j)
        bfr[j] = *(const bf16x8*)&lB[(wc + j * 16 + ml) * 64 + (((kk * 4 + qd) ^ sx) * 8)];
#pragma unroll
      for (int i = 0; i < 4; ++i)
#pragma unroll
        for (int j = 0; j < 4; ++j)
          acc[i][j] = __builtin_amdgcn_mfma_f32_16x16x32_bf16(af[i], bfr[j], acc[i][j], 0, 0, 0);
    }
    __syncthreads();
  }

  // epilogue: C/D layout col=lane&15, row=quad*4+reg
#pragma unroll
  for (int j = 0; j < 4; ++j) {
    int col = n0 + wc + j * 16 + ml;
    float bv = b2f(bi[col]);
#pragma unroll
    for (int i = 0; i < 4; ++i) {
      int row0 = m0 + wr + i * 16 + qd * 4;
      if (tstore) {
        ushort4 pk;
        pk.x = f2b((acc[i][j][0] + bv) * scl);
        pk.y = f2b((acc[i][j][1] + bv) * scl);
        pk.z = f2b((acc[i][j][2] + bv) * scl);
        pk.w = f2b((acc[i][j][3] + bv) * scl);
        *(ushort4*)((ushort*)C + (size_t)col * M + row0) = pk;
      } else if (f32out) {
        float* cp = (float*)C + (size_t)row0 * N + col;
#pragma unroll
        for (int r = 0; r < 4; ++r)
          cp[(size_t)r * N] = (acc[i][j][r] + bv) * scl;
      } else {
        ushort* cp = (ushort*)C + (size_t)row0 * N + col;
#pragma unroll
        for (int r = 0; r < 4; ++r)
          cp[(size_t)r * N] = f2b((acc[i][j][r] + bv) * scl);
      }
    }
  }
}

// ============================================================================
// Flash attention, periodic causal mask. Round-4 fixes over round 3:
//  - __launch_bounds__(256, 4): VGPR cap 128 (round-3's (256,5) cap ~96
//    caused scratch spills: WRITE_SIZE 16->210 MB, the whole regression).
//  - mid-iteration sync is raw s_barrier + explicit s_waitcnt vmcnt(0),
//    with ISSUE_K moved AFTER it: at the mid-wait only the 2 V loads are
//    outstanding (short drain), and K[kt+1] stays in flight across
//    pvstep(T0) + entire T1 phase (a __syncthreads here would drain the
//    K prefetch, destroying the overlap - round-3 bug #2).
// Kept from round 3 (VALU reductions):
//  - l-sum via ones-B MFMA (no add tree / epilogue shuffles)
//  - merged bad-column+causal 64-bit mask, post-hoc before exp2, zero C-init
//  - no online max; v_cvt_pk_bf16_f32 packing; s_setprio around MFMA
// K double-buffered, V single-buffered; 32KB LDS. global_load_lds(16B),
// XOR-swizzled tiles. 1024 blocks, XCD-swizzled.
// ============================================================================
__device__ __forceinline__ void qksm(const ushort* bK, const bf16x8 qf0, const bf16x8 qf1,
                                     int qabs, int kt, uint64_t good, bool diag,
                                     ushort* pw, int ml, int qd, int sx,
                                     bf16x8& pa0, bf16x8& pa1)
{
  const f32x4 zf = {0.f, 0.f, 0.f, 0.f};
  f32x4 sv[4];
  __builtin_amdgcn_s_setprio(1);
#pragma unroll
  for (int kb = 0; kb < 4; ++kb) {
    f32x4 s = zf;
    const ushort* krow = &bK[(kb * 16 + ml) * 64];
    s = __builtin_amdgcn_mfma_f32_16x16x32_bf16(*(const bf16x8*)&krow[(qd ^ sx) * 8],       qf0, s, 0, 0, 0);
    s = __builtin_amdgcn_mfma_f32_16x16x32_bf16(*(const bf16x8*)&krow[((qd + 4) ^ sx) * 8], qf1, s, 0, 0, 0);
    sv[kb] = s;
  }
  __builtin_amdgcn_s_setprio(0);

  // merged mask (bad columns; + causal on diagonal tile) -> -1e30 -> exp2 -> 0
  uint64_t mm = good;
  if (diag) {
    const int qrel = qabs - kt * 64;
    uint64_t keep = (qrel >= 63) ? ~0ull : ((1ull << (qrel + 1)) - 1ull);
    mm &= keep;
  }
  const uint64_t gq = mm >> (qd * 4);
  const uint32_t g_lo = (uint32_t)gq, g_hi = (uint32_t)(gq >> 32);
#pragma unroll
  for (int kb = 0; kb < 4; ++kb) {
    const uint32_t kh = (kb & 1) ? ((kb & 2) ? (g_hi >> 16) : (g_lo >> 16))
                                 : ((kb & 2) ? g_hi : g_lo);
#pragma unroll
    for (int r = 0; r < 4; ++r) {
      float x = ((kh >> r) & 1u) ? sv[kb][r] : -1.0e30f;
      sv[kb][r] = __builtin_exp2f(x);
    }
  }

  // P^T -> swizzled per-wave LDS [q][key], read back as B-frags (same wave,
  // in-order DS: no barrier needed)
  const int sub = (qd & 1) * 4;
#pragma unroll
  for (int kb = 0; kb < 4; ++kb) {
    uint32_t plo, phi;
    asm("v_cvt_pk_bf16_f32 %0, %1, %2" : "=v"(plo) : "v"(sv[kb][0]), "v"(sv[kb][1]));
    asm("v_cvt_pk_bf16_f32 %0, %1, %2" : "=v"(phi) : "v"(sv[kb][2]), "v"(sv[kb][3]));
    const int s_ = (kb * 2 + (qd >> 1)) ^ sx;
    uint2 pk; pk.x = plo; pk.y = phi;
    *(uint2*)&pw[ml * 64 + s_ * 8 + sub] = pk;
  }
  pa0 = *(const bf16x8*)&pw[ml * 64 + ((qd ^ sx)) * 8];
  pa1 = *(const bf16x8*)&pw[ml * 64 + (((qd + 4) ^ sx)) * 8];
}

__device__ __forceinline__ void pvstep(const ushort* bV, bf16x8 pa0, bf16x8 pa1,
                                       bf16x8 ones, int ml, int qd, int sx,
                                       f32x4* oaccT, f32x4& lCT)
{
  __builtin_amdgcn_s_setprio(1);
#pragma unroll
  for (int nb = 0; nb < 4; ++nb) {
    const ushort* vrow = &bV[(nb * 16 + ml) * 64];
    oaccT[nb] = __builtin_amdgcn_mfma_f32_16x16x32_bf16(*(const bf16x8*)&vrow[(qd ^ sx) * 8],       pa0, oaccT[nb], 0, 0, 0);
    oaccT[nb] = __builtin_amdgcn_mfma_f32_16x16x32_bf16(*(const bf16x8*)&vrow[((qd + 4) ^ sx) * 8], pa1, oaccT[nb], 0, 0, 0);
  }
  // l-sum: ones(A) x P^T(B): every reg = sum_k P[k][q=ml]
  lCT = __builtin_amdgcn_mfma_f32_16x16x32_bf16(ones, pa0, lCT, 0, 0, 0);
  lCT = __builtin_amdgcn_mfma_f32_16x16x32_bf16(ones, pa1, lCT, 0, 0, 0);
  __builtin_amdgcn_s_setprio(0);
}

__global__ __launch_bounds__(256, 4)
void attn_kernel(const ushort* __restrict__ Qg, const ushort* __restrict__ Kg,
                 const ushort* __restrict__ Vt, ushort* __restrict__ Og)
{
  __shared__ ushort lK[2][64 * 64];   // [key][d] swizzled, 8KB each
  __shared__ ushort lV[64 * 64];      // [d][key] swizzled, single buffer
  __shared__ ushort lP[4][16 * 64];   // per-wave P^T [q][key] swizzled
  // total 32KB

  // XCD-aware decode: xcd = lin&7; all 16 p-blocks of a bh on one XCD
  const int lin = blockIdx.x;
  const int bh  = (lin & 7) * 8 + (lin >> 7);       // 0..63
  const int p   = (lin >> 3) & 15;                  // 0..15
  const int b = bh >> 4, h = bh & 15;
  const size_t base = (size_t)b * S_ * E_ + (size_t)h * HD_;   // Q,K,O
  const ushort* vtb = Vt + (size_t)(h * HD_) * M_ + (size_t)b * S_;

  const int tid  = threadIdx.x;
  const int lane = tid & 63;
  const int wv   = tid >> 6;
  const int ml   = lane & 15;
  const int qd   = lane >> 4;
  const int sx   = ml & 7;            // XOR swizzle key for this lane's reads

  const int qthi = 31 - p, qtlo = p;
  const int q0t[2] = { qthi * 64 + wv * 16, qtlo * 64 + wv * 16 };
  const int ktmax = qthi;

  // Q B-frags: lane n=ml -> query q0t[T]+ml; k = half*32 + qd*8 + j
  bf16x8 qf[2][2];
#pragma unroll
  for (int T = 0; T < 2; ++T) {
    const ushort* qp = Qg + base + (size_t)(q0t[T] + ml) * E_ + qd * 8;
    qf[T][0] = *(const bf16x8*)qp;
    qf[T][1] = *(const bf16x8*)(qp + 32);
  }

  f32x4 oacc[2][4];
  f32x4 lC2[2];
#pragma unroll
  for (int T = 0; T < 2; ++T) {
#pragma unroll
    for (int nb = 0; nb < 4; ++nb) oacc[T][nb] = (f32x4){0.f, 0.f, 0.f, 0.f};
    lC2[T] = (f32x4){0.f, 0.f, 0.f, 0.f};
  }

  bf16x8 ones;
#pragma unroll
  for (int j = 0; j < 8; ++j) ones[j] = (short)0x3F80;   // bf16 1.0

  // staging: lane covers 16B chunk g; stored chunk s holds data chunk
  // s^(row&7) -> lane loads permuted global.
  const int g0 = (wv * 2) * 64 + lane;       // round 0 chunk id
  const int g1 = g0 + 64;                    // round 1
  const int r0 = g0 >> 3, c0 = ((g0 & 7) ^ (r0 & 7)) * 8;
  const int r1 = g1 >> 3, c1 = ((g1 & 7) ^ (r1 & 7)) * 8;
  const ushort* kS0 = Kg + base + (size_t)r0 * E_ + c0;
  const ushort* kS1 = Kg + base + (size_t)r1 * E_ + c1;
  const ushort* vS0 = vtb + (size_t)r0 * M_ + c0;
  const ushort* vS1 = vtb + (size_t)r1 * M_ + c1;
  const int d0 = (wv * 2) * 512, d1 = d0 + 512;   // ushort offsets, wave-uniform

#define ISSUE_K(bi_, t_) { size_t ko = (size_t)(t_) * 64 * E_; \
    async16(kS0 + ko, &lK[bi_][d0]); async16(kS1 + ko, &lK[bi_][d1]); }
#define ISSUE_V(t_) { int vo = (t_) * 64; \
    async16(vS0 + vo, &lV[d0]); async16(vS1 + vo, &lV[d1]); }

  ISSUE_K(0, 0);

  int rem = 0;                         // (kt*64) % JD_, incremental (+14 mod 25)
  for (int kt = 0; kt <= ktmax; ++kt) {
    __syncthreads();                   // drains K[kt]; V buffer free; prev compute done
    ISSUE_V(kt);
    const ushort* bK = lK[kt & 1];

    // bad-key bitmask for this tile: keys c, c+25, c+50 (c = JD_-1-rem)
    const int c = 24 - rem;
    rem += 14; if (rem >= 25) rem -= 25;
    const uint64_t good = ~(0x0004000002000001ull << c);

    // ---- T=0 (hi tile): QK + softmax + P staging (V latency hides here) ----
    bf16x8 pa0h, pa1h;
    qksm(bK, qf[0][0], qf[0][1], q0t[0] + ml, kt, good, kt == qthi,
         lP[wv], ml, qd, sx, pa0h, pa1h);

    // mid sync: only the 2 V loads are outstanding here -> short drain.
    asm volatile("s_waitcnt vmcnt(0)" ::: "memory");
    __builtin_amdgcn_s_barrier();      // V[kt] landed across all waves

    // K[kt+1] prefetch AFTER the mid barrier: stays in flight across
    // pvstep(T0) + whole T1 phase, drained at next top __syncthreads.
    if (kt < ktmax) ISSUE_K((kt + 1) & 1, kt + 1);

    // ---- PV for T=0 ----
    pvstep(lV, pa0h, pa1h, ones, ml, qd, sx, oacc[0], lC2[0]);

    // ---- T=1 (lo tile), while active ----
    if (kt <= qtlo) {
      bf16x8 pa0l, pa1l;
      qksm(bK, qf[1][0], qf[1][1], q0t[1] + ml, kt, good, kt == qtlo,
           lP[wv], ml, qd, sx, pa0l, pa1l);
      pvstep(lV, pa0l, pa1l, ones, ml, qd, sx, oacc[1], lC2[1]);
    }
  }
#undef ISSUE_K
#undef ISSUE_V

  // epilogue: lane owns query q0t[T]+ml; l = lC2[T][0] (all regs equal).
  // d = nb*16 + qd*4 + r (4 contiguous)
#pragma unroll
  for (int T = 0; T < 2; ++T) {
    const float inv = 1.0f / lC2[T][0];
    const int q = q0t[T] + ml;
#pragma unroll
    for (int nb = 0; nb < 4; ++nb) {
      const float a0 = oacc[T][nb][0] * inv;
      const float a1 = oacc[T][nb][1] * inv;
      const float a2 = oacc[T][nb][2] * inv;
      const float a3 = oacc[T][nb][3] * inv;
      uint32_t olo, ohi;
      asm("v_cvt_pk_bf16_f32 %0, %1, %2" : "=v"(olo) : "v"(a0), "v"(a1));
      asm("v_cvt_pk_bf16_f32 %0, %1, %2" : "=v"(ohi) : "v"(a2), "v"(a3));
      uint2 o; o.x = olo; o.y = ohi;
      *(uint2*)&Og[base + (size_t)q * E_ + nb * 16 + qd * 4] = o;
    }
  }
}

// ============================================================================
extern "C" void kernel_launch(void* const* d_in, const int* in_sizes, int n_in,
                              void* d_out, int out_size, void* d_ws, size_t ws_size,
                              hipStream_t stream) {
  const void* hs = d_in[0];
  const void* Wq = d_in[1];
  const void* bq = d_in[2];
  const void* Wk = d_in[3];
  const void* bk = d_in[4];
  const void* Wv = d_in[5];
  const void* bv = d_in[6];
  const void* Wp = d_in[7];
  const void* bp = d_in[8];

  ushort* ws = (ushort*)d_ws;
  ushort* hsb = ws + OFF_HSB;
  ushort* Wqb = ws + OFF_W(0);
  ushort* Wkb = ws + OFF_W(1);
  ushort* Wvb = ws + OFF_W(2);
  ushort* Wpb = ws + OFF_W(3);
  ushort* bqb = ws + OFF_B(0);
  ushort* bkb = ws + OFF_B(1);
  ushort* bvb = ws + OFF_B(2);
  ushort* bpb = ws + OFF_B(3);
  ushort* Qw  = ws + OFF_Q;
  ushort* Kw  = ws + OFF_K;
  ushort* Vw  = ws + OFF_V;   // V^T [feature][b*S+s]
  ushort* Ow  = ws + OFF_O;
  const ushort* det = (const ushort*)hs;

  dim3 blk(256, 1, 1);
  hipLaunchKernelGGL(convert_kernel, dim3(512, 9, 1), blk, 0, stream,
                     hs, Wq, Wk, Wv, Wp, bq, bk, bv, bp, ws);
  // fused QKV projections; z==2 (V) transposed store; z==0 (Q) scaled QSCALE
  hipLaunchKernelGGL(gemm_nt_bias, dim3(M_ / 128, E_ / 128, 3), blk, 0, stream,
                     hsb, Wqb, bqb, (void*)Qw, Wkb, bkb, (void*)Kw,
                     Wvb, bvb, (void*)Vw, M_, E_, E_, det, 0, 2, 0);
  // attention: 1024 1D blocks, XCD-swizzled
  hipLaunchKernelGGL(attn_kernel, dim3(1024, 1, 1), blk, 0, stream,
                     Qw, Kw, Vw, Ow);
  // output projection: d_out dtype detected at runtime
  hipLaunchKernelGGL(gemm_nt_bias, dim3(M_ / 128, E_ / 128, 1), blk, 0, stream,
                     Ow, Wpb, bpb, d_out, Wpb, bpb, d_out, Wpb, bpb, d_out,
                     M_, E_, E_, det, 1, -1, -1);
}